// Round 6
// baseline (733.143 us; speedup 1.0000x reference)
//
#include <hip/hip_runtime.h>
#include <hip/hip_bf16.h>

typedef unsigned int u32;
typedef unsigned short u16;
typedef __attribute__((ext_vector_type(8))) short short8;   // 8 bf16 (4 VGPRs) MFMA A/B frag
typedef __attribute__((ext_vector_type(4))) float f32x4;    // MFMA C/D frag
typedef __attribute__((ext_vector_type(4))) u32 u32x4;

#define DD 32
#define EE 8
#define HH 64
#define TT 10
#define BATCH 16384
#define EPB 32          // batch elements per block (grid 512 -> 2 blocks/CU)

__device__ __forceinline__ float fast_tanh(float x) {
  // 1 - 2/(e^{2x}+1); saturates to +/-1 at +/-inf, no NaN
  float e = __expf(2.f * x);
  return 1.f - 2.f * __builtin_amdgcn_rcpf(e + 1.f);
}
// cheap bf16 round (round-half-up): 2 VALU vs ~5 for software RNE
__device__ __forceinline__ u16 f2b_rn(float v) {
  return (u16)((__float_as_uint(v) + 0x8000u) >> 16);
}
__device__ __forceinline__ u32 pack2_rn(float a, float b) {
  return ((__float_as_uint(a) + 0x8000u) >> 16) |
         ((__float_as_uint(b) + 0x8000u) & 0xffff0000u);
}
__device__ __forceinline__ float unp_lo(u32 p) { return __uint_as_float(p << 16); }
__device__ __forceinline__ float unp_hi(u32 p) { return __uint_as_float(p & 0xffff0000u); }
__device__ __forceinline__ short8 lds_frag(const u32* p) {
  u32x4 w = *(const u32x4*)p;               // ds_read_b128 (16B-aligned by construction)
  return __builtin_bit_cast(short8, w);
}

// wave = expert (8 waves, 512 thr), 32 batch elements per block.
// Phase A: per-wave MFMA expert MLP (weights as reg B-frags).
// Gating: MFMA too (G1 1 tile/wave, G2 waves 0-1), B-frags from LDS bf16 transposes.
// Phases B/C: lane = elem (&31), half-wave picks dim/hidden slice.
__global__ __launch_bounds__(512, 4) void ame_ode_kernel(
    const float* __restrict__ x0, const float* __restrict__ tspan,
    const float* __restrict__ W1, const float* __restrict__ b1,
    const float* __restrict__ W2, const float* __restrict__ b2,
    const float* __restrict__ W3, const float* __restrict__ b3,
    const float* __restrict__ Gw1, const float* __restrict__ Gb1,
    const float* __restrict__ Gw2, const float* __restrict__ Gb2,
    float* __restrict__ out)
{
  __shared__ __align__(16) u32 xdb[EPB][36];     // cols 0-15: xs bf16x2, 16-31: dx, 4 pad (4608 B)
  __shared__ __align__(16) u32 fs[EPB][130];     // [elem][e*16 + d/2] bf16x2, stride 130 (16640 B)
  __shared__ __align__(16) float lg[EPB][9];     // gating logits (stride 9: no 4-way on write) (1152 B)
  __shared__ __align__(16) u32 hsbuf[EE * 16 * 36]; // per-wave h scratch [16][36]; aliased as gs (18432 B)
  __shared__ __align__(16) u16 gw1t[HH][72];     // Gw1^T bf16 [h][i] (9216 B)
  __shared__ __align__(16) u16 gw2t[16][72];     // Gw2^T bf16 [j][h], rows 8-15 zero (2304 B)
  // total 52352 B -> 2 blocks/CU co-resident

  const int tid  = threadIdx.x;
  const int lane = tid & 63;
  const int l15  = lane & 15;
  const int quad = lane >> 4;
  const int e    = __builtin_amdgcn_readfirstlane(tid >> 6);   // wave-uniform expert id
  const int elem = lane & 31;       // phase B/C element
  const int hf   = lane >> 5;       // half-wave select
  const int cc   = 2 * e + hf;      // owned bf16-pair column (dims 2cc, 2cc+1)
  const int d0   = 2 * cc;          // first owned dim
  const int bglob = blockIdx.x * EPB;

  const float* W1f = W1 + e * (DD + 1) * HH;
  const float* b1f = b1 + e * HH;
  const float* W2f = W2 + e * HH * HH;
  const float* b2f = b2 + e * HH;
  const float* W3f = W3 + e * HH * DD;
  const float* b3f = b3 + e * DD;

  // ---- one-time expert-weight preload into B-frags: B[k=quad*8+j][n=l15(+16nt)] ----
  short8 bw1[4], bw2[2][4], bw3[2][2];
  #pragma unroll
  for (int nt = 0; nt < 4; nt++)
    #pragma unroll
    for (int j = 0; j < 8; j++)
      bw1[nt][j] = (short)f2b_rn(W1f[(quad * 8 + j) * HH + nt * 16 + l15]);
  #pragma unroll
  for (int ks = 0; ks < 2; ks++)
    #pragma unroll
    for (int nt = 0; nt < 4; nt++)
      #pragma unroll
      for (int j = 0; j < 8; j++)
        bw2[ks][nt][j] = (short)f2b_rn(W2f[(ks * 32 + quad * 8 + j) * HH + nt * 16 + l15]);
  #pragma unroll
  for (int ks = 0; ks < 2; ks++)
    #pragma unroll
    for (int dt2 = 0; dt2 < 2; dt2++)
      #pragma unroll
      for (int j = 0; j < 8; j++)
        bw3[ks][dt2][j] = (short)f2b_rn(W3f[(ks * 32 + quad * 8 + j) * DD + dt2 * 16 + l15]);

  // per-lane C-init components, bf16-packed to save VGPRs (depend on col only)
  u32 c1p[4], c2p[2], c3p;    // c1p[nt] = (b1 | t-row), c2p = b2 pairs, c3p = b3 pair
  #pragma unroll
  for (int nt = 0; nt < 4; nt++)
    c1p[nt] = pack2_rn(b1f[nt * 16 + l15], W1f[DD * HH + nt * 16 + l15]);
  #pragma unroll
  for (int p = 0; p < 2; p++)
    c2p[p] = pack2_rn(b2f[(2 * p) * 16 + l15], b2f[(2 * p + 1) * 16 + l15]);
  c3p = pack2_rn(b3f[l15], b3f[16 + l15]);
  const float gb1v = Gb1[(e >> 1) * 16 + l15];            // G1 C-init (nt = e>>1)
  const float gb2v = (l15 < 8) ? Gb2[l15] : 0.f;          // G2 C-init

  // ---- LDS transposes of gating weights (one-time) ----
  for (int idx = tid; idx < HH * HH; idx += 512) {
    int h = idx >> 6, i = idx & 63;
    gw1t[h][i] = f2b_rn(Gw1[i * HH + h]);
  }
  for (int idx = tid; idx < 16 * HH; idx += 512) {
    int j = idx >> 6, h = idx & 63;
    gw2t[j][h] = (j < EE) ? f2b_rn(Gw2[h * EE + j]) : (u16)0;
  }

  // ---- state init: lane owns dims d0,d0+1 of elem ----
  float xst0, xst1, xac0, xac1;
  {
    const float2 v = *(const float2*)(x0 + (bglob + elem) * DD + d0);
    xst0 = v.x; xst1 = v.y; xac0 = v.x; xac1 = v.y;
    xdb[elem][cc] = pack2_rn(v.x, v.y);
    *(float2*)(out + ((bglob + elem) * TT) * DD + d0) = v;
  }
  __syncthreads();

  u32* const hw = hsbuf + e * 576;         // this wave's [16][36] scratch
  u16* const hw16 = (u16*)hw;
  u16* const fw16 = (u16*)&fs[0][0];       // stride 260 u16
  const u32* const gw1t32 = (const u32*)&gw1t[0][0];   // stride 36 u32
  const u32* const gw2t32 = (const u32*)&gw2t[0][0];
  const u16* const gs16 = (const u16*)hsbuf;           // gating-U scratch [32][72] (aliases hs)
  u16* const gsw16 = (u16*)hsbuf;

  #pragma unroll 1
  for (int step = 0; step < TT - 1; step++) {
    const float t0 = tspan[step];
    const float t1 = tspan[step + 1];
    const float dt = t1 - t0;

    #pragma unroll 1
    for (int s = 0; s < 4; s++) {
      const float tcur = (s == 0) ? t0 : ((s == 3) ? t1 : t0 + 0.5f * dt);

      // ================= Phase A: expert MLP via MFMA (M=32: 2 tiles) =================
      #pragma unroll 1
      for (int mt = 0; mt < 2; mt++) {
        const short8 a1 = lds_frag(&xdb[mt * 16 + l15][quad * 4]);
        f32x4 h1a[4];
        #pragma unroll
        for (int nt = 0; nt < 4; nt++) {
          const float iv = __builtin_fmaf(tcur, unp_hi(c1p[nt]), unp_lo(c1p[nt]));
          f32x4 c; c[0] = iv; c[1] = iv; c[2] = iv; c[3] = iv;
          h1a[nt] = __builtin_amdgcn_mfma_f32_16x16x32_bf16(a1, bw1[nt], c, 0, 0, 0);
        }
        #pragma unroll
        for (int nt = 0; nt < 4; nt++)
          #pragma unroll
          for (int r = 0; r < 4; r++)
            hw16[(quad * 4 + r) * 72 + nt * 16 + l15] = f2b_rn(fast_tanh(h1a[nt][r]));

        f32x4 h2a[4];
        #pragma unroll
        for (int nt = 0; nt < 4; nt++) {
          const float bv = (nt & 1) ? unp_hi(c2p[nt >> 1]) : unp_lo(c2p[nt >> 1]);
          f32x4 c; c[0] = bv; c[1] = bv; c[2] = bv; c[3] = bv;
          h2a[nt] = c;
        }
        #pragma unroll
        for (int ks = 0; ks < 2; ks++) {
          const short8 a2 = lds_frag(&hw[l15 * 36 + ks * 16 + quad * 4]);
          #pragma unroll
          for (int nt = 0; nt < 4; nt++)
            h2a[nt] = __builtin_amdgcn_mfma_f32_16x16x32_bf16(a2, bw2[ks][nt], h2a[nt], 0, 0, 0);
        }
        #pragma unroll
        for (int nt = 0; nt < 4; nt++)
          #pragma unroll
          for (int r = 0; r < 4; r++)
            hw16[(quad * 4 + r) * 72 + nt * 16 + l15] = f2b_rn(fast_tanh(h2a[nt][r]));

        f32x4 fa[2];
        #pragma unroll
        for (int dt2 = 0; dt2 < 2; dt2++) {
          const float bv = dt2 ? unp_hi(c3p) : unp_lo(c3p);
          f32x4 c; c[0] = bv; c[1] = bv; c[2] = bv; c[3] = bv;
          fa[dt2] = c;
        }
        #pragma unroll
        for (int ks = 0; ks < 2; ks++) {
          const short8 a3 = lds_frag(&hw[l15 * 36 + ks * 16 + quad * 4]);
          #pragma unroll
          for (int dt2 = 0; dt2 < 2; dt2++)
            fa[dt2] = __builtin_amdgcn_mfma_f32_16x16x32_bf16(a3, bw3[ks][dt2], fa[dt2], 0, 0, 0);
        }
        #pragma unroll
        for (int dt2 = 0; dt2 < 2; dt2++)
          #pragma unroll
          for (int r = 0; r < 4; r++)
            fw16[(mt * 16 + quad * 4 + r) * 260 + e * 32 + dt2 * 16 + l15] = f2b_rn(fa[dt2][r]);
      } // mt
      __syncthreads();   // A: fs complete

      // ===== B1: dx = mean_e f -> xdb cols 16-31 (lane: elem, pair cc) =====
      {
        float s0 = 0.f, s1 = 0.f;
        #pragma unroll
        for (int j = 0; j < EE; j++) {
          const u32 p = fs[elem][j * 16 + cc];
          s0 += unp_lo(p); s1 += unp_hi(p);
        }
        xdb[elem][16 + cc] = pack2_rn(s0 * 0.125f, s1 * 0.125f);
      }
      __syncthreads();   // B1: concat(xs,dx) complete

      // ===== G1: U = tanh(concat @ Gw1 + Gb1), 1 tile (mt=e&1, nt=e>>1) per wave =====
      {
        const int mt = e & 1, nt = e >> 1;
        f32x4 u; u[0] = gb1v; u[1] = gb1v; u[2] = gb1v; u[3] = gb1v;
        #pragma unroll
        for (int ks = 0; ks < 2; ks++) {
          const short8 ag = lds_frag(&xdb[mt * 16 + l15][ks * 16 + quad * 4]);
          const short8 bg = lds_frag(&gw1t32[(nt * 16 + l15) * 36 + ks * 16 + quad * 4]);
          u = __builtin_amdgcn_mfma_f32_16x16x32_bf16(ag, bg, u, 0, 0, 0);
        }
        #pragma unroll
        for (int r = 0; r < 4; r++)
          gsw16[(mt * 16 + quad * 4 + r) * 72 + nt * 16 + l15] = f2b_rn(fast_tanh(u[r]));
      }
      __syncthreads();   // G1: U complete (in gs, aliasing dead hs)

      // ===== G2: logits = U @ Gw2 + Gb2 (waves 0-1; cols j=l15<8) =====
      if (e < 2) {
        const int mt = e;
        f32x4 lv; lv[0] = gb2v; lv[1] = gb2v; lv[2] = gb2v; lv[3] = gb2v;
        #pragma unroll
        for (int ks = 0; ks < 2; ks++) {
          const short8 ag = lds_frag((const u32*)&gs16[(mt * 16 + l15) * 72 + ks * 32 + quad * 8]);
          const short8 bg = lds_frag(&gw2t32[l15 * 36 + ks * 16 + quad * 4]);
          lv = __builtin_amdgcn_mfma_f32_16x16x32_bf16(ag, bg, lv, 0, 0, 0);
        }
        if (l15 < 8) {
          #pragma unroll
          for (int r = 0; r < 4; r++)
            lg[mt * 16 + quad * 4 + r][l15] = lv[r];
        }
      }
      __syncthreads();   // G2: logits complete

      // ===== C: softmax + weighted sum + RK4 update (lane: elem, dims d0,d0+1) =====
      {
        float la[EE];
        #pragma unroll
        for (int j = 0; j < EE; j++) la[j] = lg[elem][j];
        float m = la[0];
        #pragma unroll
        for (int j = 1; j < EE; j++) m = fmaxf(m, la[j]);
        float w8[EE], ss = 0.f;
        #pragma unroll
        for (int j = 0; j < EE; j++) { w8[j] = __expf(la[j] - m); ss += w8[j]; }
        const float inv = __builtin_amdgcn_rcpf(ss);

        float k0 = 0.f, k1 = 0.f;
        #pragma unroll
        for (int j = 0; j < EE; j++) {
          const float wg = w8[j] * inv;
          const u32 p = fs[elem][j * 16 + cc];
          k0 = __builtin_fmaf(wg, unp_lo(p), k0);
          k1 = __builtin_fmaf(wg, unp_hi(p), k1);
        }

        const float wk = (s == 1 || s == 2) ? 2.f : 1.f;
        const float ak = dt * (1.f / 6.f) * wk;
        xac0 = __builtin_fmaf(ak, k0, xac0);
        xac1 = __builtin_fmaf(ak, k1, xac1);

        float xn0, xn1;
        if (s < 3) {
          const float cn = (s == 2) ? dt : 0.5f * dt;
          xn0 = __builtin_fmaf(cn, k0, xst0);
          xn1 = __builtin_fmaf(cn, k1, xst1);
        } else {
          xst0 = xac0; xst1 = xac1; xn0 = xac0; xn1 = xac1;
          float2 o; o.x = xn0; o.y = xn1;
          *(float2*)(out + ((bglob + elem) * TT + step + 1) * DD + d0) = o;
        }
        xdb[elem][cc] = pack2_rn(xn0, xn1);
      }
      __syncthreads();   // end of stage
    } // stages
  } // steps
}

extern "C" void kernel_launch(void* const* d_in, const int* in_sizes, int n_in,
                              void* d_out, int out_size, void* d_ws, size_t ws_size,
                              hipStream_t stream)
{
  const float* x0    = (const float*)d_in[0];
  const float* tspan = (const float*)d_in[1];
  const float* W1  = (const float*)d_in[2];
  const float* b1  = (const float*)d_in[3];
  const float* W2  = (const float*)d_in[4];
  const float* b2  = (const float*)d_in[5];
  const float* W3  = (const float*)d_in[6];
  const float* b3  = (const float*)d_in[7];
  const float* Gw1 = (const float*)d_in[8];
  const float* Gb1 = (const float*)d_in[9];
  const float* Gw2 = (const float*)d_in[10];
  const float* Gb2 = (const float*)d_in[11];

  ame_ode_kernel<<<BATCH / EPB, 512, 0, stream>>>(
      x0, tspan, W1, b1, W2, b2, W3, b3, Gw1, Gb1, Gw2, Gb2, (float*)d_out);
}

// Round 7
// 370.370 us; speedup vs baseline: 1.9795x; 1.9795x over previous
//
#include <hip/hip_runtime.h>
#include <hip/hip_bf16.h>

typedef unsigned int u32;
typedef unsigned short u16;
typedef __attribute__((ext_vector_type(8))) short short8;   // 8 bf16 (4 VGPRs) MFMA A/B frag
typedef __attribute__((ext_vector_type(4))) float f32x4;    // MFMA C/D frag
typedef __attribute__((ext_vector_type(4))) u32 u32x4;

#define DD 32
#define EE 8
#define HH 64
#define TT 10
#define BATCH 16384
#define EPB 32          // batch elements per block (grid 512)

__device__ __forceinline__ float fast_tanh(float x) {
  // 1 - 2/(e^{2x}+1); saturates to +/-1 at +/-inf, no NaN
  float e = __expf(2.f * x);
  return 1.f - 2.f * __builtin_amdgcn_rcpf(e + 1.f);
}
// cheap bf16 round (round-half-up): 2 VALU vs ~5 for software RNE
__device__ __forceinline__ u16 f2b_rn(float v) {
  return (u16)((__float_as_uint(v) + 0x8000u) >> 16);
}
__device__ __forceinline__ u32 pack2_rn(float a, float b) {
  return ((__float_as_uint(a) + 0x8000u) >> 16) |
         ((__float_as_uint(b) + 0x8000u) & 0xffff0000u);
}
__device__ __forceinline__ float unp_lo(u32 p) { return __uint_as_float(p << 16); }
__device__ __forceinline__ float unp_hi(u32 p) { return __uint_as_float(p & 0xffff0000u); }
__device__ __forceinline__ short8 lds_frag(const u32* p) {
  u32x4 w = *(const u32x4*)p;               // ds_read_b128 (16B-aligned by construction)
  return __builtin_bit_cast(short8, w);
}

// wave = expert (8 waves, 512 thr), 32 batch elements per block.
// Phase A: per-wave MFMA expert MLP, weights held in registers as B-frags.
// REGISTER POLICY (round-6 lesson): no min-occupancy launch_bounds — capping
// VGPR at 128 makes the allocator dump the 64-VGPR weight frags and re-fetch
// weights from global every stage (FETCH 2.4 MB -> 1.77 GB, dur 658 -> 733).
// 2 waves/SIMD with frags resident beats 4 waves/SIMD with remat.
__global__ __launch_bounds__(512) void ame_ode_kernel(
    const float* __restrict__ x0, const float* __restrict__ tspan,
    const float* __restrict__ W1, const float* __restrict__ b1,
    const float* __restrict__ W2, const float* __restrict__ b2,
    const float* __restrict__ W3, const float* __restrict__ b3,
    const float* __restrict__ Gw1, const float* __restrict__ Gb1,
    const float* __restrict__ Gw2, const float* __restrict__ Gb2,
    float* __restrict__ out)
{
  __shared__ __align__(16) u32 xdb[EPB][36];     // cols 0-15: xs bf16x2, 16-31: dx, 4 pad (4608 B)
  __shared__ __align__(16) u32 fs[EPB][130];     // [elem][e*16 + d/2] bf16x2 (16640 B)
  __shared__ __align__(16) float lg[EPB][9];     // gating logits (1152 B)
  __shared__ __align__(16) u32 hsbuf[EE * 16 * 36]; // per-wave h scratch [16][36]; aliased as gs (18432 B)
  __shared__ __align__(16) u16 gw1t[HH][72];     // Gw1^T bf16 [h][i] (9216 B)
  __shared__ __align__(16) u16 gw2t[16][72];     // Gw2^T bf16 [j][h], rows 8-15 zero (2304 B)

  const int tid  = threadIdx.x;
  const int lane = tid & 63;
  const int l15  = lane & 15;
  const int quad = lane >> 4;
  const int e    = __builtin_amdgcn_readfirstlane(tid >> 6);   // wave-uniform expert id
  const int elem = lane & 31;       // phase B/C element
  const int hf   = lane >> 5;       // half-wave select
  const int cc   = 2 * e + hf;      // owned bf16-pair column (dims 2cc, 2cc+1)
  const int d0   = 2 * cc;          // first owned dim
  const int bglob = blockIdx.x * EPB;

  const float* W1f = W1 + e * (DD + 1) * HH;
  const float* b1f = b1 + e * HH;
  const float* W2f = W2 + e * HH * HH;
  const float* b2f = b2 + e * HH;
  const float* W3f = W3 + e * HH * DD;
  const float* b3f = b3 + e * DD;

  // ---- one-time expert-weight preload into B-frags: B[k=quad*8+j][n=l15(+16nt)] ----
  short8 bw1[4], bw2[2][4], bw3[2][2];
  #pragma unroll
  for (int nt = 0; nt < 4; nt++)
    #pragma unroll
    for (int j = 0; j < 8; j++)
      bw1[nt][j] = (short)f2b_rn(W1f[(quad * 8 + j) * HH + nt * 16 + l15]);
  #pragma unroll
  for (int ks = 0; ks < 2; ks++)
    #pragma unroll
    for (int nt = 0; nt < 4; nt++)
      #pragma unroll
      for (int j = 0; j < 8; j++)
        bw2[ks][nt][j] = (short)f2b_rn(W2f[(ks * 32 + quad * 8 + j) * HH + nt * 16 + l15]);
  #pragma unroll
  for (int ks = 0; ks < 2; ks++)
    #pragma unroll
    for (int dt2 = 0; dt2 < 2; dt2++)
      #pragma unroll
      for (int j = 0; j < 8; j++)
        bw3[ks][dt2][j] = (short)f2b_rn(W3f[(ks * 32 + quad * 8 + j) * DD + dt2 * 16 + l15]);

  // per-lane C-init components, bf16-packed (depend on col only)
  u32 c1p[4], c2p[2], c3p;
  #pragma unroll
  for (int nt = 0; nt < 4; nt++)
    c1p[nt] = pack2_rn(b1f[nt * 16 + l15], W1f[DD * HH + nt * 16 + l15]);
  #pragma unroll
  for (int p = 0; p < 2; p++)
    c2p[p] = pack2_rn(b2f[(2 * p) * 16 + l15], b2f[(2 * p + 1) * 16 + l15]);
  c3p = pack2_rn(b3f[l15], b3f[16 + l15]);
  const float gb1v = Gb1[(e >> 1) * 16 + l15];            // G1 C-init (nt = e>>1)
  const float gb2v = (l15 < 8) ? Gb2[l15] : 0.f;          // G2 C-init

  // ---- LDS transposes of gating weights (one-time) ----
  for (int idx = tid; idx < HH * HH; idx += 512) {
    int h = idx >> 6, i = idx & 63;
    gw1t[h][i] = f2b_rn(Gw1[i * HH + h]);
  }
  for (int idx = tid; idx < 16 * HH; idx += 512) {
    int j = idx >> 6, h = idx & 63;
    gw2t[j][h] = (j < EE) ? f2b_rn(Gw2[h * EE + j]) : (u16)0;
  }

  // ---- state init: lane owns dims d0,d0+1 of elem ----
  float xst0, xst1, xac0, xac1;
  {
    const float2 v = *(const float2*)(x0 + (bglob + elem) * DD + d0);
    xst0 = v.x; xst1 = v.y; xac0 = v.x; xac1 = v.y;
    xdb[elem][cc] = pack2_rn(v.x, v.y);
    *(float2*)(out + ((bglob + elem) * TT) * DD + d0) = v;
  }
  __syncthreads();

  u32* const hw = hsbuf + e * 576;         // this wave's [16][36] scratch
  u16* const hw16 = (u16*)hw;
  u16* const fw16 = (u16*)&fs[0][0];       // stride 260 u16
  const u32* const gw1t32 = (const u32*)&gw1t[0][0];   // stride 36 u32
  const u32* const gw2t32 = (const u32*)&gw2t[0][0];
  const u16* const gs16 = (const u16*)hsbuf;           // gating-U scratch (aliases hs)
  u16* const gsw16 = (u16*)hsbuf;

  #pragma unroll 1
  for (int step = 0; step < TT - 1; step++) {
    const float t0 = tspan[step];
    const float t1 = tspan[step + 1];
    const float dt = t1 - t0;

    #pragma unroll 1
    for (int s = 0; s < 4; s++) {
      const float tcur = (s == 0) ? t0 : ((s == 3) ? t1 : t0 + 0.5f * dt);

      // ================= Phase A: expert MLP via MFMA (M=32: 2 tiles, unrolled for ILP) =================
      #pragma unroll
      for (int mt = 0; mt < 2; mt++) {
        const short8 a1 = lds_frag(&xdb[mt * 16 + l15][quad * 4]);
        f32x4 h1a[4];
        #pragma unroll
        for (int nt = 0; nt < 4; nt++) {
          const float iv = __builtin_fmaf(tcur, unp_hi(c1p[nt]), unp_lo(c1p[nt]));
          f32x4 c; c[0] = iv; c[1] = iv; c[2] = iv; c[3] = iv;
          h1a[nt] = __builtin_amdgcn_mfma_f32_16x16x32_bf16(a1, bw1[nt], c, 0, 0, 0);
        }
        #pragma unroll
        for (int nt = 0; nt < 4; nt++)
          #pragma unroll
          for (int r = 0; r < 4; r++)
            hw16[(quad * 4 + r) * 72 + nt * 16 + l15] = f2b_rn(fast_tanh(h1a[nt][r]));

        f32x4 h2a[4];
        #pragma unroll
        for (int nt = 0; nt < 4; nt++) {
          const float bv = (nt & 1) ? unp_hi(c2p[nt >> 1]) : unp_lo(c2p[nt >> 1]);
          f32x4 c; c[0] = bv; c[1] = bv; c[2] = bv; c[3] = bv;
          h2a[nt] = c;
        }
        #pragma unroll
        for (int ks = 0; ks < 2; ks++) {
          const short8 a2 = lds_frag(&hw[l15 * 36 + ks * 16 + quad * 4]);
          #pragma unroll
          for (int nt = 0; nt < 4; nt++)
            h2a[nt] = __builtin_amdgcn_mfma_f32_16x16x32_bf16(a2, bw2[ks][nt], h2a[nt], 0, 0, 0);
        }
        #pragma unroll
        for (int nt = 0; nt < 4; nt++)
          #pragma unroll
          for (int r = 0; r < 4; r++)
            hw16[(quad * 4 + r) * 72 + nt * 16 + l15] = f2b_rn(fast_tanh(h2a[nt][r]));

        f32x4 fa[2];
        #pragma unroll
        for (int dt2 = 0; dt2 < 2; dt2++) {
          const float bv = dt2 ? unp_hi(c3p) : unp_lo(c3p);
          f32x4 c; c[0] = bv; c[1] = bv; c[2] = bv; c[3] = bv;
          fa[dt2] = c;
        }
        #pragma unroll
        for (int ks = 0; ks < 2; ks++) {
          const short8 a3 = lds_frag(&hw[l15 * 36 + ks * 16 + quad * 4]);
          #pragma unroll
          for (int dt2 = 0; dt2 < 2; dt2++)
            fa[dt2] = __builtin_amdgcn_mfma_f32_16x16x32_bf16(a3, bw3[ks][dt2], fa[dt2], 0, 0, 0);
        }
        #pragma unroll
        for (int dt2 = 0; dt2 < 2; dt2++)
          #pragma unroll
          for (int r = 0; r < 4; r++)
            fw16[(mt * 16 + quad * 4 + r) * 260 + e * 32 + dt2 * 16 + l15] = f2b_rn(fa[dt2][r]);
      } // mt
      __syncthreads();   // A: fs complete

      // ===== B1: dx = mean_e f -> xdb cols 16-31 (lane: elem, pair cc) =====
      {
        float s0 = 0.f, s1 = 0.f;
        #pragma unroll
        for (int j = 0; j < EE; j++) {
          const u32 p = fs[elem][j * 16 + cc];
          s0 += unp_lo(p); s1 += unp_hi(p);
        }
        xdb[elem][16 + cc] = pack2_rn(s0 * 0.125f, s1 * 0.125f);
      }
      __syncthreads();   // B1: concat(xs,dx) complete

      // ===== G1: U = tanh(concat @ Gw1 + Gb1), 1 tile (mt=e&1, nt=e>>1) per wave =====
      {
        const int mt = e & 1, nt = e >> 1;
        f32x4 u; u[0] = gb1v; u[1] = gb1v; u[2] = gb1v; u[3] = gb1v;
        #pragma unroll
        for (int ks = 0; ks < 2; ks++) {
          const short8 ag = lds_frag(&xdb[mt * 16 + l15][ks * 16 + quad * 4]);
          const short8 bg = lds_frag(&gw1t32[(nt * 16 + l15) * 36 + ks * 16 + quad * 4]);
          u = __builtin_amdgcn_mfma_f32_16x16x32_bf16(ag, bg, u, 0, 0, 0);
        }
        #pragma unroll
        for (int r = 0; r < 4; r++)
          gsw16[(mt * 16 + quad * 4 + r) * 72 + nt * 16 + l15] = f2b_rn(fast_tanh(u[r]));
      }
      __syncthreads();   // G1: U complete (in gs, aliasing dead hs)

      // ===== G2: logits = U @ Gw2 + Gb2 (waves 0-1; cols j=l15<8) =====
      if (e < 2) {
        const int mt = e;
        f32x4 lv; lv[0] = gb2v; lv[1] = gb2v; lv[2] = gb2v; lv[3] = gb2v;
        #pragma unroll
        for (int ks = 0; ks < 2; ks++) {
          const short8 ag = lds_frag((const u32*)&gs16[(mt * 16 + l15) * 72 + ks * 32 + quad * 8]);
          const short8 bg = lds_frag(&gw2t32[l15 * 36 + ks * 16 + quad * 4]);
          lv = __builtin_amdgcn_mfma_f32_16x16x32_bf16(ag, bg, lv, 0, 0, 0);
        }
        if (l15 < 8) {
          #pragma unroll
          for (int r = 0; r < 4; r++)
            lg[mt * 16 + quad * 4 + r][l15] = lv[r];
        }
      }
      __syncthreads();   // G2: logits complete

      // ===== C: softmax + weighted sum + RK4 update (lane: elem, dims d0,d0+1) =====
      {
        float la[EE];
        #pragma unroll
        for (int j = 0; j < EE; j++) la[j] = lg[elem][j];
        float m = la[0];
        #pragma unroll
        for (int j = 1; j < EE; j++) m = fmaxf(m, la[j]);
        float w8[EE], ss = 0.f;
        #pragma unroll
        for (int j = 0; j < EE; j++) { w8[j] = __expf(la[j] - m); ss += w8[j]; }
        const float inv = __builtin_amdgcn_rcpf(ss);

        float k0 = 0.f, k1 = 0.f;
        #pragma unroll
        for (int j = 0; j < EE; j++) {
          const float wg = w8[j] * inv;
          const u32 p = fs[elem][j * 16 + cc];
          k0 = __builtin_fmaf(wg, unp_lo(p), k0);
          k1 = __builtin_fmaf(wg, unp_hi(p), k1);
        }

        const float wk = (s == 1 || s == 2) ? 2.f : 1.f;
        const float ak = dt * (1.f / 6.f) * wk;
        xac0 = __builtin_fmaf(ak, k0, xac0);
        xac1 = __builtin_fmaf(ak, k1, xac1);

        float xn0, xn1;
        if (s < 3) {
          const float cn = (s == 2) ? dt : 0.5f * dt;
          xn0 = __builtin_fmaf(cn, k0, xst0);
          xn1 = __builtin_fmaf(cn, k1, xst1);
        } else {
          xst0 = xac0; xst1 = xac1; xn0 = xac0; xn1 = xac1;
          float2 o; o.x = xn0; o.y = xn1;
          *(float2*)(out + ((bglob + elem) * TT + step + 1) * DD + d0) = o;
        }
        xdb[elem][cc] = pack2_rn(xn0, xn1);
      }
      __syncthreads();   // end of stage
    } // stages
  } // steps
}

extern "C" void kernel_launch(void* const* d_in, const int* in_sizes, int n_in,
                              void* d_out, int out_size, void* d_ws, size_t ws_size,
                              hipStream_t stream)
{
  const float* x0    = (const float*)d_in[0];
  const float* tspan = (const float*)d_in[1];
  const float* W1  = (const float*)d_in[2];
  const float* b1  = (const float*)d_in[3];
  const float* W2  = (const float*)d_in[4];
  const float* b2  = (const float*)d_in[5];
  const float* W3  = (const float*)d_in[6];
  const float* b3  = (const float*)d_in[7];
  const float* Gw1 = (const float*)d_in[8];
  const float* Gb1 = (const float*)d_in[9];
  const float* Gw2 = (const float*)d_in[10];
  const float* Gb2 = (const float*)d_in[11];

  ame_ode_kernel<<<BATCH / EPB, 512, 0, stream>>>(
      x0, tspan, W1, b1, W2, b2, W3, b3, Gw1, Gb1, Gw2, Gb2, (float*)d_out);
}

// Round 8
// 328.892 us; speedup vs baseline: 2.2291x; 1.1261x over previous
//
#include <hip/hip_runtime.h>
#include <hip/hip_bf16.h>

typedef unsigned int u32;
typedef unsigned short u16;
typedef __attribute__((ext_vector_type(8))) short short8;   // 8 bf16 (4 VGPRs) MFMA A/B frag
typedef __attribute__((ext_vector_type(4))) float f32x4;    // MFMA C/D frag
typedef __attribute__((ext_vector_type(4))) u32 u32x4;
typedef __attribute__((ext_vector_type(2))) u32 u32x2;

#define DD 32
#define EE 8
#define HH 64
#define TT 10
#define BATCH 16384
#define EPB 64          // batch elements per block (grid 256 = 1 block/CU, no tail)

__device__ __forceinline__ float fast_tanh(float x) {
  // 1 - 2/(e^{2x}+1); saturates to +/-1 at +/-inf, no NaN
  float e = __expf(2.f * x);
  return 1.f - 2.f * __builtin_amdgcn_rcpf(e + 1.f);
}
// cheap bf16 round (round-half-up): 2 VALU vs ~5 for software RNE
__device__ __forceinline__ u16 f2b_rn(float v) {
  return (u16)((__float_as_uint(v) + 0x8000u) >> 16);
}
__device__ __forceinline__ u32 pack2_rn(float a, float b) {
  // [b.hi16 | a.hi16] after rounding: 2 adds + v_perm
  return __builtin_amdgcn_perm(__float_as_uint(b) + 0x8000u,
                               __float_as_uint(a) + 0x8000u, 0x07060302u);
}
__device__ __forceinline__ float unp_lo(u32 p) { return __uint_as_float(p << 16); }
__device__ __forceinline__ float unp_hi(u32 p) { return __uint_as_float(p & 0xffff0000u); }
__device__ __forceinline__ short8 lds_frag(const u32* p) {
  u32x4 w = *(const u32x4*)p;               // ds_read_b128 (16B-aligned by construction)
  return __builtin_bit_cast(short8, w);
}
__device__ __forceinline__ f32x4 bcast4(float v) { f32x4 c; c[0]=v; c[1]=v; c[2]=v; c[3]=v; return c; }

// wave = expert (8 waves, 512 thr), 64 batch elements per block, grid 256.
// Phase A: per-wave MFMA expert MLP (4 M-tiles), weights as register B-frags.
// Gating G1/G2 also MFMA, with Gw1/Gw2 B-frags in registers (not LDS).
// REGISTER POLICY (round-6 lesson): no min-occupancy launch_bounds — capping
// VGPR at 128 makes the allocator dump the weight frags and re-fetch from
// global every stage (FETCH 2.4 MB -> 1.77 GB). Frags resident > occupancy.
__global__ __launch_bounds__(512) void ame_ode_kernel(
    const float* __restrict__ x0, const float* __restrict__ tspan,
    const float* __restrict__ W1, const float* __restrict__ b1,
    const float* __restrict__ W2, const float* __restrict__ b2,
    const float* __restrict__ W3, const float* __restrict__ b3,
    const float* __restrict__ Gw1, const float* __restrict__ Gb1,
    const float* __restrict__ Gw2, const float* __restrict__ Gb2,
    float* __restrict__ out)
{
  __shared__ __align__(16) u32 xdb[EPB][36];     // cols 0-15 xs, 16-31 dx (bf16x2), 4 pad (9216 B)
  __shared__ __align__(16) u32 fs[EPB][130];     // [elem][e*16 + d/2] bf16x2 (33280 B)
  __shared__ __align__(16) float lg[EPB][12];    // logits, stride 12 -> aligned float4 (3072 B)
  __shared__ __align__(16) u32 hsbuf[EE * 16 * 36]; // per-wave h scratch; aliased as U for G1/G2 (18432 B)
  // total 64000 B (<= 64 KB static limit), 1 block/CU

  const int tid  = threadIdx.x;
  const int lane = tid & 63;
  const int l15  = lane & 15;
  const int quad = lane >> 4;
  const int e    = __builtin_amdgcn_readfirstlane(tid >> 6);   // wave-uniform expert id
  const int b    = blockIdx.x * EPB + lane;                    // this lane's batch element

  const float* W1f = W1 + e * (DD + 1) * HH;
  const float* b1f = b1 + e * HH;
  const float* W2f = W2 + e * HH * HH;
  const float* b2f = b2 + e * HH;
  const float* W3f = W3 + e * HH * DD;
  const float* b3f = b3 + e * DD;

  // ---- one-time expert-weight preload into B-frags: B[k=quad*8+j][n=l15(+16nt)] ----
  short8 bw1[4], bw2[2][4], bw3[2][2];
  #pragma unroll
  for (int nt = 0; nt < 4; nt++)
    #pragma unroll
    for (int j = 0; j < 8; j++)
      bw1[nt][j] = (short)f2b_rn(W1f[(quad * 8 + j) * HH + nt * 16 + l15]);
  #pragma unroll
  for (int ks = 0; ks < 2; ks++)
    #pragma unroll
    for (int nt = 0; nt < 4; nt++)
      #pragma unroll
      for (int j = 0; j < 8; j++)
        bw2[ks][nt][j] = (short)f2b_rn(W2f[(ks * 32 + quad * 8 + j) * HH + nt * 16 + l15]);
  #pragma unroll
  for (int ks = 0; ks < 2; ks++)
    #pragma unroll
    for (int dt2 = 0; dt2 < 2; dt2++)
      #pragma unroll
      for (int j = 0; j < 8; j++)
        bw3[ks][dt2][j] = (short)f2b_rn(W3f[(ks * 32 + quad * 8 + j) * DD + dt2 * 16 + l15]);

  // gating weights as register B-frags (removes 11.5 KB LDS + per-stage reads)
  const int g1mt = e & 3;              // G1 tile assignment: wave e -> M-tile e&3,
  const int g1n0 = (e >> 2) * 2;       //                     N-tiles (e>>2)*2, +1
  short8 bg1[2][2];                    // [ni][ks]
  #pragma unroll
  for (int ni = 0; ni < 2; ni++)
    #pragma unroll
    for (int ks = 0; ks < 2; ks++)
      #pragma unroll
      for (int j = 0; j < 8; j++)
        bg1[ni][ks][j] = (short)f2b_rn(Gw1[(ks * 32 + quad * 8 + j) * HH + (g1n0 + ni) * 16 + l15]);
  const float gb1a = Gb1[g1n0 * 16 + l15];
  const float gb1b = Gb1[(g1n0 + 1) * 16 + l15];

  short8 bg2[2];
  float gb2v = 0.f;
  if (e < 4) {                         // G2: waves 0-3, M-tile = e
    #pragma unroll
    for (int ks = 0; ks < 2; ks++)
      #pragma unroll
      for (int j = 0; j < 8; j++)
        bg2[ks][j] = (short)((l15 < 8) ? f2b_rn(Gw2[(ks * 32 + quad * 8 + j) * EE + l15]) : 0);
    gb2v = (l15 < 8) ? Gb2[l15] : 0.f;
  }

  // per-lane C-init components (depend on col only); c2/c3 hoisted as vectors
  u32 c1p[4];
  #pragma unroll
  for (int nt = 0; nt < 4; nt++)
    c1p[nt] = pack2_rn(b1f[nt * 16 + l15], W1f[DD * HH + nt * 16 + l15]);
  f32x4 c2i[4], c3i[2];
  #pragma unroll
  for (int nt = 0; nt < 4; nt++) c2i[nt] = bcast4(b2f[nt * 16 + l15]);
  #pragma unroll
  for (int dt2 = 0; dt2 < 2; dt2++) c3i[dt2] = bcast4(b3f[dt2 * 16 + l15]);

  // ---- state init: lane owns dims 4e..4e+3 of elem = lane ----
  float xst[4], xacc[4];
  {
    const float4 v = *(const float4*)(x0 + b * DD + 4 * e);
    xst[0] = v.x; xst[1] = v.y; xst[2] = v.z; xst[3] = v.w;
    xacc[0] = v.x; xacc[1] = v.y; xacc[2] = v.z; xacc[3] = v.w;
    u32x2 p; p.x = pack2_rn(v.x, v.y); p.y = pack2_rn(v.z, v.w);
    *(u32x2*)&xdb[lane][2 * e] = p;
    *(float4*)(out + b * TT * DD + 4 * e) = v;
  }
  __syncthreads();

  u32* const hw   = hsbuf + e * 576;         // this wave's [16][36] u32 scratch
  u16* const hw16 = (u16*)hw;
  u16* const fw16 = (u16*)&fs[0][0];         // stride 260 u16
  u16* const uw16 = (u16*)hsbuf;             // U matrix (G1 out), row stride 72 u16
  const u32* const u32v = hsbuf;             // U as u32, row stride 36

  #pragma unroll 1
  for (int step = 0; step < TT - 1; step++) {
    const float t0 = tspan[step];
    const float t1 = tspan[step + 1];
    const float dt = t1 - t0;

    #pragma unroll 1
    for (int s = 0; s < 4; s++) {
      const float tcur = (s == 0) ? t0 : ((s == 3) ? t1 : t0 + 0.5f * dt);

      f32x4 c1i[4];
      #pragma unroll
      for (int nt = 0; nt < 4; nt++)
        c1i[nt] = bcast4(__builtin_fmaf(tcur, unp_hi(c1p[nt]), unp_lo(c1p[nt])));

      // ================= Phase A: expert MLP via MFMA (M=64: 4 tiles) =================
      #pragma unroll 2
      for (int mt = 0; mt < 4; mt++) {
        const short8 a1 = lds_frag(&xdb[mt * 16 + l15][quad * 4]);
        f32x4 h1a[4];
        #pragma unroll
        for (int nt = 0; nt < 4; nt++)
          h1a[nt] = __builtin_amdgcn_mfma_f32_16x16x32_bf16(a1, bw1[nt], c1i[nt], 0, 0, 0);
        #pragma unroll
        for (int nt = 0; nt < 4; nt++)
          #pragma unroll
          for (int r = 0; r < 4; r++)
            hw16[(quad * 4 + r) * 72 + nt * 16 + l15] = f2b_rn(fast_tanh(h1a[nt][r]));

        f32x4 h2a[4];
        #pragma unroll
        for (int nt = 0; nt < 4; nt++) h2a[nt] = c2i[nt];
        #pragma unroll
        for (int ks = 0; ks < 2; ks++) {
          const short8 a2 = lds_frag(&hw[l15 * 36 + ks * 16 + quad * 4]);
          #pragma unroll
          for (int nt = 0; nt < 4; nt++)
            h2a[nt] = __builtin_amdgcn_mfma_f32_16x16x32_bf16(a2, bw2[ks][nt], h2a[nt], 0, 0, 0);
        }
        #pragma unroll
        for (int nt = 0; nt < 4; nt++)
          #pragma unroll
          for (int r = 0; r < 4; r++)
            hw16[(quad * 4 + r) * 72 + nt * 16 + l15] = f2b_rn(fast_tanh(h2a[nt][r]));

        f32x4 fa[2];
        #pragma unroll
        for (int dt2 = 0; dt2 < 2; dt2++) fa[dt2] = c3i[dt2];
        #pragma unroll
        for (int ks = 0; ks < 2; ks++) {
          const short8 a3 = lds_frag(&hw[l15 * 36 + ks * 16 + quad * 4]);
          #pragma unroll
          for (int dt2 = 0; dt2 < 2; dt2++)
            fa[dt2] = __builtin_amdgcn_mfma_f32_16x16x32_bf16(a3, bw3[ks][dt2], fa[dt2], 0, 0, 0);
        }
        #pragma unroll
        for (int dt2 = 0; dt2 < 2; dt2++)
          #pragma unroll
          for (int r = 0; r < 4; r++)
            fw16[(mt * 16 + quad * 4 + r) * 260 + e * 32 + dt2 * 16 + l15] = f2b_rn(fa[dt2][r]);
      } // mt
      __syncthreads();   // A: fs complete

      // ===== B1: dx = mean_e f -> xdb cols 16-31 (lane = elem, dims 4e..4e+3) =====
      {
        float s0 = 0.f, s1 = 0.f, s2 = 0.f, s3 = 0.f;
        #pragma unroll
        for (int j = 0; j < EE; j++) {
          const u32x2 p = *(const u32x2*)&fs[lane][j * 16 + 2 * e];
          s0 += unp_lo(p.x); s1 += unp_hi(p.x);
          s2 += unp_lo(p.y); s3 += unp_hi(p.y);
        }
        u32x2 w; w.x = pack2_rn(s0 * 0.125f, s1 * 0.125f);
        w.y = pack2_rn(s2 * 0.125f, s3 * 0.125f);
        *(u32x2*)&xdb[lane][16 + 2 * e] = w;
      }
      __syncthreads();   // B1: concat(xs,dx) complete

      // ===== G1: U = tanh(concat @ Gw1 + Gb1); 2 of 16 tiles per wave =====
      {
        f32x4 u0 = bcast4(gb1a), u1 = bcast4(gb1b);
        #pragma unroll
        for (int ks = 0; ks < 2; ks++) {
          const short8 ag = lds_frag(&xdb[g1mt * 16 + l15][ks * 16 + quad * 4]);
          u0 = __builtin_amdgcn_mfma_f32_16x16x32_bf16(ag, bg1[0][ks], u0, 0, 0, 0);
          u1 = __builtin_amdgcn_mfma_f32_16x16x32_bf16(ag, bg1[1][ks], u1, 0, 0, 0);
        }
        #pragma unroll
        for (int r = 0; r < 4; r++) {
          uw16[(g1mt * 16 + quad * 4 + r) * 72 + g1n0 * 16 + l15]       = f2b_rn(fast_tanh(u0[r]));
          uw16[(g1mt * 16 + quad * 4 + r) * 72 + (g1n0 + 1) * 16 + l15] = f2b_rn(fast_tanh(u1[r]));
        }
      }
      __syncthreads();   // G1: U complete

      // ===== G2: logits = U @ Gw2 + Gb2 (waves 0-3, M-tile = e) =====
      if (e < 4) {
        f32x4 lv = bcast4(gb2v);
        #pragma unroll
        for (int ks = 0; ks < 2; ks++) {
          const short8 ag = lds_frag(&u32v[(e * 16 + l15) * 36 + ks * 16 + quad * 4]);
          lv = __builtin_amdgcn_mfma_f32_16x16x32_bf16(ag, bg2[ks], lv, 0, 0, 0);
        }
        if (l15 < 8) {
          #pragma unroll
          for (int r = 0; r < 4; r++)
            lg[e * 16 + quad * 4 + r][l15] = lv[r];
        }
      }
      __syncthreads();   // G2: logits complete

      // ===== C: softmax + weighted sum + RK4 update (lane = elem, dims 4e..4e+3) =====
      {
        const float4 la0 = *(const float4*)&lg[lane][0];
        const float4 la1 = *(const float4*)&lg[lane][4];
        float m = fmaxf(fmaxf(fmaxf(la0.x, la0.y), fmaxf(la0.z, la0.w)),
                        fmaxf(fmaxf(la1.x, la1.y), fmaxf(la1.z, la1.w)));
        float w8[EE];
        w8[0] = __expf(la0.x - m); w8[1] = __expf(la0.y - m);
        w8[2] = __expf(la0.z - m); w8[3] = __expf(la0.w - m);
        w8[4] = __expf(la1.x - m); w8[5] = __expf(la1.y - m);
        w8[6] = __expf(la1.z - m); w8[7] = __expf(la1.w - m);
        float ss = 0.f;
        #pragma unroll
        for (int j = 0; j < EE; j++) ss += w8[j];
        const float inv = __builtin_amdgcn_rcpf(ss);

        float kc[4] = {0.f, 0.f, 0.f, 0.f};
        #pragma unroll
        for (int j = 0; j < EE; j++) {
          const float wg = w8[j] * inv;
          const u32x2 p = *(const u32x2*)&fs[lane][j * 16 + 2 * e];
          kc[0] = __builtin_fmaf(wg, unp_lo(p.x), kc[0]);
          kc[1] = __builtin_fmaf(wg, unp_hi(p.x), kc[1]);
          kc[2] = __builtin_fmaf(wg, unp_lo(p.y), kc[2]);
          kc[3] = __builtin_fmaf(wg, unp_hi(p.y), kc[3]);
        }

        const float wk = (s == 1 || s == 2) ? 2.f : 1.f;
        const float ak = dt * (1.f / 6.f) * wk;
        #pragma unroll
        for (int q = 0; q < 4; q++) xacc[q] = __builtin_fmaf(ak, kc[q], xacc[q]);

        float xn[4];
        if (s < 3) {
          const float cn = (s == 2) ? dt : 0.5f * dt;
          #pragma unroll
          for (int q = 0; q < 4; q++) xn[q] = __builtin_fmaf(cn, kc[q], xst[q]);
        } else {
          #pragma unroll
          for (int q = 0; q < 4; q++) { xst[q] = xacc[q]; xn[q] = xacc[q]; }
          float4 o; o.x = xn[0]; o.y = xn[1]; o.z = xn[2]; o.w = xn[3];
          *(float4*)(out + (b * TT + step + 1) * DD + 4 * e) = o;
        }
        u32x2 p; p.x = pack2_rn(xn[0], xn[1]); p.y = pack2_rn(xn[2], xn[3]);
        *(u32x2*)&xdb[lane][2 * e] = p;
      }
      __syncthreads();   // end of stage
    } // stages
  } // steps
}

extern "C" void kernel_launch(void* const* d_in, const int* in_sizes, int n_in,
                              void* d_out, int out_size, void* d_ws, size_t ws_size,
                              hipStream_t stream)
{
  const float* x0    = (const float*)d_in[0];
  const float* tspan = (const float*)d_in[1];
  const float* W1  = (const float*)d_in[2];
  const float* b1  = (const float*)d_in[3];
  const float* W2  = (const float*)d_in[4];
  const float* b2  = (const float*)d_in[5];
  const float* W3  = (const float*)d_in[6];
  const float* b3  = (const float*)d_in[7];
  const float* Gw1 = (const float*)d_in[8];
  const float* Gb1 = (const float*)d_in[9];
  const float* Gw2 = (const float*)d_in[10];
  const float* Gb2 = (const float*)d_in[11];

  ame_ode_kernel<<<BATCH / EPB, 512, 0, stream>>>(
      x0, tspan, W1, b1, W2, b2, W3, b3, Gw1, Gb1, Gw2, Gb2, (float*)d_out);
}